// Round 6
// baseline (114.177 us; speedup 1.0000x reference)
//
#include <hip/hip_runtime.h>
#include <math.h>

// Problem constants (from reference setup_inputs)
static constexpr int B_TOTAL = 131072;
static constexpr int M_MOD   = 14;    // NB_MOD_MAX + 2
static constexpr int C_DIM   = 128;   // CONCEPT_N
static constexpr int CPB     = 8;     // chunks of 16 elements per block

// ---------- DPP helpers (verified exact in R5): 16-lane row reduces ----------
template <int CTRL>
__device__ __forceinline__ float dpp_mov(float x) {
    return __int_as_float(__builtin_amdgcn_update_dpp(
        0, __float_as_int(x), CTRL, 0xF, 0xF, true));
}
#define ROW_SUM(x)                                                             \
    do {                                                                       \
        x += dpp_mov<0x128>(x); /* row_ror:8 */                                \
        x += dpp_mov<0x124>(x); /* row_ror:4 */                                \
        x += dpp_mov<0x04E>(x); /* quad_perm(2,3,0,1) = xor 2 */               \
        x += dpp_mov<0x0B1>(x); /* quad_perm(1,0,3,2) = xor 1 */               \
    } while (0)
#define ROW_MIN(x)                                                             \
    do {                                                                       \
        x = fminf(x, dpp_mov<0x128>(x));                                       \
        x = fminf(x, dpp_mov<0x124>(x));                                       \
        x = fminf(x, dpp_mov<0x04E>(x));                                       \
        x = fminf(x, dpp_mov<0x0B1>(x));                                       \
    } while (0)

// ---------- Prologue: G[c] = W[c] W[c]^T (6 uniques, padded to 8) ----------
__global__ __launch_bounds__(64) void gram_kernel(
    const float* __restrict__ W, float* __restrict__ g)
{
    const int c = blockIdx.x;
    const int l = threadIdx.x;
    const float2* wp = (const float2*)(W + (size_t)c * 3 * C_DIM);
    const float2 a0 = wp[l], a1 = wp[64 + l], a2 = wp[128 + l];
    float g00 = a0.x * a0.x + a0.y * a0.y;
    float g01 = a0.x * a1.x + a0.y * a1.y;
    float g02 = a0.x * a2.x + a0.y * a2.y;
    float g11 = a1.x * a1.x + a1.y * a1.y;
    float g12 = a1.x * a2.x + a1.y * a2.y;
    float g22 = a2.x * a2.x + a2.y * a2.y;
#pragma unroll
    for (int off = 32; off; off >>= 1) {
        g00 += __shfl_xor(g00, off, 64);
        g01 += __shfl_xor(g01, off, 64);
        g02 += __shfl_xor(g02, off, 64);
        g11 += __shfl_xor(g11, off, 64);
        g12 += __shfl_xor(g12, off, 64);
        g22 += __shfl_xor(g22, off, 64);
    }
    if (l == 0) {
        float* o = g + c * 8;
        o[0] = g00; o[1] = g01; o[2] = g02;
        o[3] = g11; o[4] = g12; o[5] = g22;
        o[6] = 0.f; o[7] = 0.f;
    }
}

// ---------- Main: 16 lanes/element, 8 iterations/block, pipelined ----------
// Pipeline: ids prefetched 2 iterations ahead; u-row (the HBM-latency load)
// prefetched 1 ahead into a 2-deep rotating buffer. W/gram/pr are small
// L2-hot tables loaded in-iteration. Grid (1024 blocks x 4 waves) is fully
// co-resident at 16 waves/CU.
__global__ __launch_bounds__(256, 4) void impact_kernel(
    const int*   __restrict__ user_ids,
    const int*   __restrict__ item_ids,
    const int*   __restrict__ concept_ids,
    const float* __restrict__ users_emb,   // (USER_N, 128)
    const float* __restrict__ item_resp,   // (ITEM_N * 14, 3)
    const float* __restrict__ W,           // (128, 3, 128)
    const int*   __restrict__ nb_mod,      // (ITEM_N,)
    const float* __restrict__ gram,        // (128, 8) in d_ws
    float*       __restrict__ out)         // (B,)
{
    const int s    = threadIdx.x & 15;                 // sublane in group
    const int g    = threadIdx.x >> 4;                 // group id in block
    const int base = blockIdx.x * (CPB * 16) + g;      // element for t=0

    int uid[CPB], iid[CPB], cid[CPB];
    float4 uA[2], uB[2];

    // Pipeline prologue: ids for t=0,1; u for t=0.
    uid[0] = user_ids[base];      iid[0] = item_ids[base];
    cid[0] = concept_ids[base];
    uid[1] = user_ids[base + 16]; iid[1] = item_ids[base + 16];
    cid[1] = concept_ids[base + 16];
    {
        const float4* up = (const float4*)(users_emb + (size_t)uid[0] * C_DIM);
        uA[0] = up[s]; uB[0] = up[s + 16];
    }

#pragma unroll
    for (int t = 0; t < CPB; ++t) {
        // Prefetch ids two iterations ahead.
        if (t + 2 < CPB) {
            const int bn = base + (t + 2) * 16;
            uid[t + 2] = user_ids[bn];
            iid[t + 2] = item_ids[bn];
            cid[t + 2] = concept_ids[bn];
        }
        // Prefetch next u row (HBM gather — the long pole).
        if (t + 1 < CPB) {
            const float4* up =
                (const float4*)(users_emb + (size_t)uid[t + 1] * C_DIM);
            uA[(t + 1) & 1] = up[s];
            uB[(t + 1) & 1] = up[s + 16];
        }

        const int I  = iid[t];
        const int Cc = cid[t];
        const int nb = nb_mod[I];
        // W_t rows (196 KB table -> L2-hot).
        const float4* wp = (const float4*)(W + (size_t)Cc * 3 * C_DIM);
        const float4 w0a = wp[s],      w0b = wp[16 + s];
        const float4 w1a = wp[32 + s], w1b = wp[48 + s];
        const float4 w2a = wp[64 + s], w2b = wp[80 + s];
        // Gram (4 KB table) and this lane's modality row (j = s+1).
        const float4 gA = ((const float4*)(gram + Cc * 8))[0];
        const float4 gB = ((const float4*)(gram + Cc * 8))[1];
        const float* pj =
            item_resp + ((size_t)I * M_MOD + (s < 12 ? s + 1 : 1)) * 3;
        const float p0 = pj[0], p1 = pj[1], p2 = pj[2];

        const float4 uAc = uA[t & 1], uBc = uB[t & 1];
        float v0 = 0.f, v1 = 0.f, v2 = 0.f;
#define COL(uc, a0, a1, a2)                                                    \
        do {                                                                   \
            v0 = fmaf((a0), (uc), v0);                                         \
            v1 = fmaf((a1), (uc), v1);                                         \
            v2 = fmaf((a2), (uc), v2);                                         \
        } while (0)
        COL(uAc.x, w0a.x, w1a.x, w2a.x);
        COL(uAc.y, w0a.y, w1a.y, w2a.y);
        COL(uAc.z, w0a.z, w1a.z, w2a.z);
        COL(uAc.w, w0a.w, w1a.w, w2a.w);
        COL(uBc.x, w0b.x, w1b.x, w2b.x);
        COL(uBc.y, w0b.y, w1b.y, w2b.y);
        COL(uBc.z, w0b.z, w1b.z, w2b.z);
        COL(uBc.w, w0b.w, w1b.w, w2b.w);
#undef COL
        ROW_SUM(v0);
        ROW_SUM(v1);
        ROW_SUM(v2);

        // Score j = s+1 (valid iff j <= nb; nb >= 2 so the min is finite).
        float m = INFINITY;
        if (s < 12 && (s + 1) <= nb) {
            const float dot = fmaf(p0, v0, fmaf(p1, v1, p2 * v2));
            float q = p0 * p0 * gA.x;           // g00
            q = fmaf(p1 * p1, gA.w, q);         // g11
            q = fmaf(p2 * p2, gB.y, q);         // g22
            q = fmaf(2.0f * p0 * p1, gA.y, q);  // g01
            q = fmaf(2.0f * p0 * p2, gA.z, q);  // g02
            q = fmaf(2.0f * p1 * p2, gB.x, q);  // g12
            m = fmaf(-2.0f, dot, q);
        }
        float bm = m;
        ROW_MIN(bm);
        const unsigned long long mask = __ballot(m == bm);
        if (s == 0) {
            const unsigned slice = (unsigned)((mask >> ((g & 3) * 16)) & 0xffffu);
            const int jm1 = __builtin_ctz(slice);   // lane s ↔ j=s+1
            out[base + t * 16] = (float)jm1 / (float)(nb - 1) + 1.0f;
        }
    }
}

extern "C" void kernel_launch(void* const* d_in, const int* in_sizes, int n_in,
                              void* d_out, int out_size, void* d_ws, size_t ws_size,
                              hipStream_t stream) {
    const int*   user_ids    = (const int*)d_in[0];
    const int*   item_ids    = (const int*)d_in[1];
    const int*   concept_ids = (const int*)d_in[2];
    const float* users_emb   = (const float*)d_in[3];
    const float* item_resp   = (const float*)d_in[4];
    const float* W           = (const float*)d_in[5];
    // d_in[6] = mask: unused — validity recomputed from nb_modalities.
    const int*   nb_mod      = (const int*)d_in[7];
    float*       gram        = (float*)d_ws;   // 128*8 floats = 4 KB
    float*       out         = (float*)d_out;

    gram_kernel<<<dim3(128), dim3(64), 0, stream>>>(W, gram);
    impact_kernel<<<dim3(B_TOTAL / (CPB * 16)), dim3(256), 0, stream>>>(
        user_ids, item_ids, concept_ids, users_emb, item_resp, W, nb_mod,
        gram, out);
}